// Round 16
// baseline (301.966 us; speedup 1.0000x reference)
//
#include <hip/hip_runtime.h>

typedef __bf16 bf16x8 __attribute__((ext_vector_type(8)));
typedef __bf16 bf16x4 __attribute__((ext_vector_type(4)));
typedef float  f32x4  __attribute__((ext_vector_type(4)));
typedef float  f32x16 __attribute__((ext_vector_type(16)));

#define DEVI __device__ __forceinline__

DEVI bf16x8 ld8(const __bf16* p) { return *reinterpret_cast<const bf16x8*>(p); }
DEVI f32x4 mfma16(bf16x8 a, bf16x8 b, f32x4 c) {
  return __builtin_amdgcn_mfma_f32_16x16x32_bf16(a, b, c, 0, 0, 0);
}
DEVI f32x16 mfma32(bf16x8 a, bf16x8 b, f32x16 c) {
  return __builtin_amdgcn_mfma_f32_32x32x16_bf16(a, b, c, 0, 0, 0);
}
DEVI void gl_lds16(const void* g, void* l) {
  __builtin_amdgcn_global_load_lds((__attribute__((address_space(1))) void*)g,
                                   (__attribute__((address_space(3))) void*)l, 16, 0, 0);
}
DEVI unsigned pk2(float a, float b) {
  union { __bf16 h[2]; unsigned u; } x;
  x.h[0] = (__bf16)a; x.h[1] = (__bf16)b; return x.u;
}

#if __has_builtin(__builtin_amdgcn_exp2f)
#define EXP2(x) __builtin_amdgcn_exp2f(x)
#else
#define EXP2(x) exp2f(x)
#endif

// ---------- fused prep: x cvt + Wq/Wk/Wv transpose + Wo hi/lo transpose ----------
__global__ __launch_bounds__(256) void k_prep(
    const float* __restrict__ x, const float* __restrict__ Wq,
    const float* __restrict__ Wk, const float* __restrict__ Wv,
    const float* __restrict__ Wo, __bf16* __restrict__ xb,
    __bf16* __restrict__ Wt, __bf16* __restrict__ Woh, __bf16* __restrict__ Wol) {
  const int bid = blockIdx.x;
  if (bid < 1024) {
    const int i = bid * 256 + threadIdx.x;
    f32x4 v = reinterpret_cast<const f32x4*>(x)[i];
    bf16x4 o;
    o[0] = (__bf16)v[0]; o[1] = (__bf16)v[1]; o[2] = (__bf16)v[2]; o[3] = (__bf16)v[3];
    reinterpret_cast<bf16x4*>(xb)[i] = o;
    return;
  }
  __shared__ float t[32][33];
  const int flat = bid - 1024;
  const float* in; __bf16* oh; __bf16* ol = nullptr;
  int R, C, c0, r0;
  bool lo = false;
  if (flat < 1536) {
    const int which = flat >> 9, rem = flat & 511;
    const int h = rem >> 6, tt = rem & 63;
    c0 = (tt & 7) * 32; r0 = (tt >> 3) * 32;
    const float* Wsrc = which == 0 ? Wq : which == 1 ? Wk : Wv;
    in = Wsrc + h * 65536;
    oh = Wt + which * 524288 + h * 65536;
    R = 256; C = 256;
  } else {
    const int rem = flat - 1536;
    c0 = (rem & 7) * 32; r0 = (rem >> 3) * 32;
    in = Wo; oh = Woh; ol = Wol; lo = true;
    R = 2048; C = 256;
  }
  const int tx = threadIdx.x & 31, ty = threadIdx.x >> 5;
  #pragma unroll
  for (int k = 0; k < 32; k += 8)
    t[ty + k][tx] = in[(size_t)(r0 + ty + k) * C + c0 + tx];
  __syncthreads();
  #pragma unroll
  for (int k = 0; k < 32; k += 8) {
    const float v = t[tx][ty + k];
    const size_t o = (size_t)(c0 + ty + k) * R + r0 + tx;
    const __bf16 h = (__bf16)v;
    oh[o] = h;
    if (lo) ol[o] = (__bf16)(v - (float)h);
  }
}

// ---------- QKV projection: Q+K merged per block (shared x frags), V separate ----------
__global__ __launch_bounds__(256) void k_qkv(
    const __bf16* __restrict__ xb, const __bf16* __restrict__ Wt,
    const float* __restrict__ bq, const float* __restrict__ bk, const float* __restrict__ bv,
    __bf16* __restrict__ Qb, __bf16* __restrict__ Kb, __bf16* __restrict__ Vtb) {
  const int wl = threadIdx.x >> 6, lane = threadIdx.x & 63;
  const int g = lane >> 4, qc = lane & 15;
  const int h = blockIdx.z >> 1, isV = blockIdx.z & 1;
  const int sblk = blockIdx.x * 256;
  const int s0 = sblk + wl * 64;
  const int e0 = blockIdx.y * 64;
  const int b = sblk >> 11;
  const int bh = b * 8 + h;
  const int sm0 = s0 & 2047;

  if (isV) {
    const __bf16* Wm = Wt + 2 * 524288 + (size_t)h * 65536;
    const float* bias = bv + h * 256;
    f32x4 acc[4][4] = {};
    #pragma unroll
    for (int kk = 0; kk < 8; kk++) {
      bf16x8 af[4], bf[4];
      #pragma unroll
      for (int ai = 0; ai < 4; ai++)
        af[ai] = ld8(xb + (size_t)(s0 + ai * 16 + qc) * 256 + kk * 32 + g * 8);
      #pragma unroll
      for (int bj = 0; bj < 4; bj++)
        bf[bj] = ld8(Wm + (size_t)(e0 + bj * 16 + qc) * 256 + kk * 32 + g * 8);
      #pragma unroll
      for (int ai = 0; ai < 4; ai++)
        #pragma unroll
        for (int bj = 0; bj < 4; bj++)
          acc[ai][bj] = mfma16(af[ai], bf[bj], acc[ai][bj]);
    }
    #pragma unroll
    for (int bj = 0; bj < 4; bj++) {
      const int e = e0 + bj * 16 + qc;
      const float be = bias[e];
      #pragma unroll
      for (int ai = 0; ai < 4; ai++) {
        bf16x4 pk;
        #pragma unroll
        for (int r = 0; r < 4; r++) pk[r] = (__bf16)(acc[ai][bj][r] + be);
        *reinterpret_cast<bf16x4*>(Vtb + ((size_t)(bh * 256 + e)) * 2048 +
                                   sm0 + ai * 16 + g * 4) = pk;
      }
    }
  } else {
    const __bf16* WmQ = Wt + (size_t)h * 65536;
    const __bf16* WmK = Wt + 524288 + (size_t)h * 65536;
    f32x4 accq[4][4] = {}, acck[4][4] = {};
    #pragma unroll
    for (int kk = 0; kk < 8; kk++) {
      bf16x8 aq[4], ak[4], bf[4];
      #pragma unroll
      for (int ai = 0; ai < 4; ai++) {
        aq[ai] = ld8(WmQ + (size_t)(e0 + ai * 16 + qc) * 256 + kk * 32 + g * 8);
        ak[ai] = ld8(WmK + (size_t)(e0 + ai * 16 + qc) * 256 + kk * 32 + g * 8);
      }
      #pragma unroll
      for (int bj = 0; bj < 4; bj++)
        bf[bj] = ld8(xb + (size_t)(s0 + bj * 16 + qc) * 256 + kk * 32 + g * 8);
      #pragma unroll
      for (int ai = 0; ai < 4; ai++)
        #pragma unroll
        for (int bj = 0; bj < 4; bj++) {
          accq[ai][bj] = mfma16(aq[ai], bf[bj], accq[ai][bj]);
          acck[ai][bj] = mfma16(ak[ai], bf[bj], acck[ai][bj]);
        }
    }
    // Q folds 1/sqrt(D) * log2(e)  (attention runs in exp2 domain)
    const float sc = 0.0625f * 1.4426950408889634f;
    #pragma unroll
    for (int ai = 0; ai < 4; ai++) {
      float beq[4], bek[4];
      #pragma unroll
      for (int r = 0; r < 4; r++) {
        beq[r] = bq[h * 256 + e0 + ai * 16 + g * 4 + r];
        bek[r] = bk[h * 256 + e0 + ai * 16 + g * 4 + r];
      }
      #pragma unroll
      for (int bj = 0; bj < 4; bj++) {
        const int srow = sm0 + bj * 16 + qc;
        const size_t base = ((size_t)(bh * 2048 + srow)) * 256 + e0 + ai * 16 + g * 4;
        bf16x4 pq, pk;
        #pragma unroll
        for (int r = 0; r < 4; r++) {
          pq[r] = (__bf16)((accq[ai][bj][r] + beq[r]) * sc);
          pk[r] = (__bf16)(acck[ai][bj][r] + bek[r]);
        }
        *reinterpret_cast<bf16x4*>(Qb + base) = pq;
        *reinterpret_cast<bf16x4*>(Kb + base) = pk;
      }
    }
  }
}

// ---------- flash attention v13: d-split for 2 blocks/CU ----------
// grid 512 (16bh x 32qt of 64q) x 256 thr. Wave w: q-sub = w&1 (32 q),
// d-half = w>>1 (128 d). acc = 4x f32x16 (64 regs) -> total regs ~200 ->
// 2 waves/SIMD. QK^T duplicated across d-halves (+50% MFMA) to buy TLP.
// KVBLK=32, LDS 64KB (2 blocks = 128KB <= 160). All swizzles = R15-proven.
__global__ __launch_bounds__(256) void k_attn(
    const __bf16* __restrict__ Qb, const __bf16* __restrict__ Kb,
    const __bf16* __restrict__ Vtb, __bf16* __restrict__ Oh, __bf16* __restrict__ Ol) {
  __shared__ __align__(16) unsigned char smem[65536];
  const int tid = threadIdx.x;
  const int wl = tid >> 6, lane = tid & 63;
  const int hi = lane >> 5, q = lane & 31;
  const int qs = wl & 1, dh = wl >> 1;

  const int bid = blockIdx.x;
  const int s = (bid & 7) * 64 + (bid >> 3);      // XCD-chunked swizzle (512%8==0)
  const int bh = s >> 5, qt = s & 31;

  const int q0w = qt * 64 + qs * 32;
  const char* Kg = (const char*)Kb + ((size_t)bh * 2048) * 512;
  const char* Vg = (const char*)Vtb + (size_t)bh * 256 * 4096;
  const __bf16* Qp = Qb + ((size_t)(bh * 2048 + q0w + q)) * 256;

  bf16x8 qf[16];
  #pragma unroll
  for (int kk = 0; kk < 16; kk++) qf[kk] = ld8(Qp + kk * 16 + hi * 8);

  f32x16 acc[4];
  #pragma unroll
  for (int i = 0; i < 4; i++)
    #pragma unroll
    for (int e = 0; e < 16; e++) acc[i][e] = 0.f;

  // stage one 32-kv tile: K 16KB ([32 kv][512B], 4-bit XOR) +
  // V 16KB (64B/d units: [32 sb][8 dlo][4 ch], ch XOR sb&3) — R15 geometry.
  auto stage = [&](int nb, int t) {
    unsigned char* kbp = smem + nb * 16384 + wl * 4096;
    unsigned char* vbp = smem + 32768 + nb * 16384 + wl * 4096;
    #pragma unroll
    for (int j = 0; j < 4; j++) {
      const int O = wl * 4096 + j * 1024 + lane * 16;
      const int kv = O >> 9;
      const int c = ((O >> 4) & 31) ^ (kv & 15);
      gl_lds16(Kg + (size_t)t * 16384 + (size_t)kv * 512 + c * 16, kbp + j * 1024);
    }
    #pragma unroll
    for (int j = 0; j < 4; j++) {
      const int O = wl * 4096 + j * 1024 + lane * 16;
      const int sb = O >> 9;
      const int dlo = (O >> 6) & 7;
      const int ch = (O >> 4) & 3;
      const int d = sb * 8 + dlo;
      gl_lds16(Vg + (size_t)d * 4096 + (size_t)t * 64 + ((ch ^ (sb & 3)) << 4),
               vbp + j * 1024);
    }
  };

  float m_run = -3.0e38f, l_run = 0.f;
  stage(0, 0);
  __syncthreads();

  for (int t = 0; t < 64; t++) {
    const int cur = t & 1;
    const unsigned char* kbc = smem + cur * 16384;
    const unsigned char* vbc = smem + 32768 + cur * 16384;
    if (t < 63) stage(cur ^ 1, t + 1);

    // ---- QK^T (swapped): st = S^T[kv=q][q-col], 16-MFMA chain ----
    f32x16 st;
    #pragma unroll
    for (int e = 0; e < 16; e++) st[e] = 0.f;
    #pragma unroll
    for (int kk = 0; kk < 16; kk++) {
      const int o0 = q * 512 + ((((kk << 1) + hi) ^ (q & 15)) << 4);
      bf16x8 kf = *reinterpret_cast<const bf16x8*>(kbc + o0);
      st = mfma32(kf, qf[kk], st);
    }

    // ---- online softmax over 32 values, exp2 domain, defer-max THR=8 ----
    f32x16 mx = st;
    #pragma unroll
    for (int w2 = 8; w2 > 0; w2 >>= 1)
      #pragma unroll
      for (int r = 0; r < w2; r++) mx[r] = fmaxf(mx[r], mx[r + w2]);
    const float rmax = fmaxf(mx[0], __shfl_xor(mx[0], 32));
    if (__any(rmax > m_run + 8.0f)) {
      const float m_new = fmaxf(rmax, m_run);
      const float alpha = EXP2(m_run - m_new);
      m_run = m_new;
      l_run *= alpha;
      #pragma unroll
      for (int r = 0; r < 16; r++) {
        const float ar = __shfl(alpha, (r & 3) + 8 * (r >> 2) + 4 * hi);
        #pragma unroll
        for (int dt = 0; dt < 4; dt++) acc[dt][r] *= ar;
      }
    }
    f32x16 sm_;
    #pragma unroll
    for (int r = 0; r < 16; r++) {
      st[r] = EXP2(st[r] - m_run);
      sm_[r] = st[r];
    }
    #pragma unroll
    for (int w2 = 8; w2 > 0; w2 >>= 1)
      #pragma unroll
      for (int r = 0; r < w2; r++) sm_[r] += sm_[r + w2];
    l_run += sm_[0] + __shfl_xor(sm_[0], 32);

    // ---- P -> 2 PV A-frags in-register (pk2 + shfl_xor exchange, proven) ----
    bf16x8 pa[2];
    #pragma unroll
    for (int c = 0; c < 2; c++) {
      const unsigned L0 = pk2(st[c * 8 + 0], st[c * 8 + 1]);
      const unsigned L1 = pk2(st[c * 8 + 2], st[c * 8 + 3]);
      const unsigned H0 = pk2(st[c * 8 + 4], st[c * 8 + 5]);
      const unsigned H1 = pk2(st[c * 8 + 6], st[c * 8 + 7]);
      const unsigned xL0 = __shfl_xor(L0, 32), xL1 = __shfl_xor(L1, 32);
      const unsigned xH0 = __shfl_xor(H0, 32), xH1 = __shfl_xor(H1, 32);
      unsigned pw[4];
      pw[0] = hi ? xH0 : L0;  pw[1] = hi ? xH1 : L1;
      pw[2] = hi ? H0 : xL0;  pw[3] = hi ? H1 : xL1;
      pa[c] = *reinterpret_cast<bf16x8*>(pw);
    }

    // ---- PV: acc[dt] col = d = dh*128 + dt*32 + q ----
    #pragma unroll
    for (int dt = 0; dt < 4; dt++) {
      const int d = dh * 128 + dt * 32 + q;
      const int sb = d >> 3;
      const int base = sb * 512 + (d & 7) * 64;
      const int key = sb & 3;
      #pragma unroll
      for (int c = 0; c < 2; c++) {
        const int off = base + ((((c << 1) | hi) ^ key) << 4);
        bf16x8 vf = *reinterpret_cast<const bf16x8*>(vbc + off);
        acc[dt] = mfma32(pa[c], vf, acc[dt]);
      }
    }
    __syncthreads();
  }

  // ---- epilogue: divide by l, split hi/lo bf16 ----
  float linv[16];
  #pragma unroll
  for (int r = 0; r < 16; r++)
    linv[r] = 1.f / __shfl(l_run, (r & 3) + 8 * (r >> 2) + 4 * hi);
  const int b = bh >> 3, h = bh & 7;
  #pragma unroll
  for (int dt = 0; dt < 4; dt++) {
    #pragma unroll
    for (int r = 0; r < 16; r++) {
      const float v = acc[dt][r] * linv[r];
      const int qrow = (r & 3) + 8 * (r >> 2) + 4 * hi;
      const size_t off = (size_t)b * (2048 * 2048) +
                         (size_t)(q0w + qrow) * 2048 + h * 256 + dh * 128 + dt * 32 + q;
      const __bf16 hv = (__bf16)v;
      Oh[off] = hv;
      Ol[off] = (__bf16)(v - (float)hv);
    }
  }
}

// ---------- output projection, K-split x4 + atomic accumulate ----------
__global__ __launch_bounds__(256) void k_out(
    const __bf16* __restrict__ Oh, const __bf16* __restrict__ Ol,
    const __bf16* __restrict__ Wh, const __bf16* __restrict__ Wl,
    const float* __restrict__ bo, float* __restrict__ out) {
  const int w = threadIdx.x >> 6, lane = threadIdx.x & 63;
  const int g = lane >> 4, qc = lane & 15;
  const int m0 = blockIdx.x * 64 + w * 16, n0 = blockIdx.y * 64;
  const int k0 = blockIdx.z * 512;
  f32x4 acc[4] = {};
  const __bf16* ah_p = Oh + (size_t)(m0 + qc) * 2048 + k0 + g * 8;
  const __bf16* al_p = Ol + (size_t)(m0 + qc) * 2048 + k0 + g * 8;
  for (int kk = 0; kk < 16; kk++) {
    bf16x8 ah = ld8(ah_p + kk * 32);
    bf16x8 al = ld8(al_p + kk * 32);
    #pragma unroll
    for (int nt = 0; nt < 4; nt++) {
      const size_t nrow = (size_t)(n0 + nt * 16 + qc) * 2048 + k0 + kk * 32 + g * 8;
      bf16x8 bh = ld8(Wh + nrow);
      bf16x8 bl = ld8(Wl + nrow);
      acc[nt] = mfma16(ah, bh, acc[nt]);
      acc[nt] = mfma16(al, bh, acc[nt]);
      acc[nt] = mfma16(ah, bl, acc[nt]);
    }
  }
  #pragma unroll
  for (int nt = 0; nt < 4; nt++) {
    const int n = n0 + nt * 16 + qc;
    const float bb = (blockIdx.z == 0) ? bo[n] : 0.f;
    #pragma unroll
    for (int r = 0; r < 4; r++)
      unsafeAtomicAdd(&out[(m0 + g * 4 + r) * 256 + n], acc[nt][r] + bb);
  }
}

extern "C" void kernel_launch(void* const* d_in, const int* in_sizes, int n_in,
                              void* d_out, int out_size, void* d_ws, size_t ws_size,
                              hipStream_t stream) {
  const float* x  = (const float*)d_in[0];
  const float* Wq = (const float*)d_in[1];
  const float* bq = (const float*)d_in[2];
  const float* Wk = (const float*)d_in[3];
  const float* bk = (const float*)d_in[4];
  const float* Wv = (const float*)d_in[5];
  const float* bv = (const float*)d_in[6];
  const float* Wo = (const float*)d_in[7];
  const float* bo = (const float*)d_in[8];
  char* p = (char*)d_ws;
  __bf16* xb  = (__bf16*)(p);                          // 2 MB  [4096][256]
  __bf16* Wt  = (__bf16*)(p + (2ull  << 20));          // 3 MB  [3][8][256 e][256 d]
  __bf16* Woh = (__bf16*)(p + (5ull  << 20));          // 1 MB  [256 n][2048 k]
  __bf16* Wol = (__bf16*)(p + (6ull  << 20));          // 1 MB
  __bf16* Qb  = (__bf16*)(p + (7ull  << 20));          // 16 MB [bh][s][d] (scale folded)
  __bf16* Kb  = (__bf16*)(p + (23ull << 20));          // 16 MB [bh][s][d]
  __bf16* Vtb = (__bf16*)(p + (39ull << 20));          // 16 MB [bh][d][s]
  __bf16* Ohb = (__bf16*)(p + (55ull << 20));          // 16 MB [bs][h*d] hi
  __bf16* Olb = (__bf16*)(p + (71ull << 20));          // 16 MB [bs][h*d] lo

  k_prep<<<dim3(3072), dim3(256), 0, stream>>>(x, Wq, Wk, Wv, Wo, xb, Wt, Woh, Wol);
  k_qkv<<<dim3(16, 4, 16), dim3(256), 0, stream>>>(xb, Wt, bq, bk, bv, Qb, Kb, Vtb);
  k_attn<<<dim3(512), dim3(256), 0, stream>>>(Qb, Kb, Vtb, Ohb, Olb);
  (void)hipMemsetAsync(d_out, 0, (size_t)out_size * sizeof(float), stream);
  k_out<<<dim3(64, 4, 4), dim3(256), 0, stream>>>(Ohb, Olb, Woh, Wol, bo, (float*)d_out);
}

// Round 17
// 251.549 us; speedup vs baseline: 1.2004x; 1.2004x over previous
//
#include <hip/hip_runtime.h>

typedef __bf16 bf16x8 __attribute__((ext_vector_type(8)));
typedef __bf16 bf16x4 __attribute__((ext_vector_type(4)));
typedef float  f32x4  __attribute__((ext_vector_type(4)));
typedef float  f32x16 __attribute__((ext_vector_type(16)));

#define DEVI __device__ __forceinline__

DEVI bf16x8 ld8(const __bf16* p) { return *reinterpret_cast<const bf16x8*>(p); }
DEVI f32x4 mfma16(bf16x8 a, bf16x8 b, f32x4 c) {
  return __builtin_amdgcn_mfma_f32_16x16x32_bf16(a, b, c, 0, 0, 0);
}
DEVI f32x16 mfma32(bf16x8 a, bf16x8 b, f32x16 c) {
  return __builtin_amdgcn_mfma_f32_32x32x16_bf16(a, b, c, 0, 0, 0);
}
DEVI void gl_lds16(const void* g, void* l) {
  __builtin_amdgcn_global_load_lds((__attribute__((address_space(1))) void*)g,
                                   (__attribute__((address_space(3))) void*)l, 16, 0, 0);
}
DEVI unsigned pk2(float a, float b) {
  union { __bf16 h[2]; unsigned u; } x;
  x.h[0] = (__bf16)a; x.h[1] = (__bf16)b; return x.u;
}

#if __has_builtin(__builtin_amdgcn_exp2f)
#define EXP2(x) __builtin_amdgcn_exp2f(x)
#else
#define EXP2(x) exp2f(x)
#endif

// ---------- fused prep: x cvt + Wq/Wk/Wv transpose + Wo hi/lo transpose ----------
__global__ __launch_bounds__(256) void k_prep(
    const float* __restrict__ x, const float* __restrict__ Wq,
    const float* __restrict__ Wk, const float* __restrict__ Wv,
    const float* __restrict__ Wo, __bf16* __restrict__ xb,
    __bf16* __restrict__ Wt, __bf16* __restrict__ Woh, __bf16* __restrict__ Wol) {
  const int bid = blockIdx.x;
  if (bid < 1024) {
    const int i = bid * 256 + threadIdx.x;
    f32x4 v = reinterpret_cast<const f32x4*>(x)[i];
    bf16x4 o;
    o[0] = (__bf16)v[0]; o[1] = (__bf16)v[1]; o[2] = (__bf16)v[2]; o[3] = (__bf16)v[3];
    reinterpret_cast<bf16x4*>(xb)[i] = o;
    return;
  }
  __shared__ float t[32][33];
  const int flat = bid - 1024;
  const float* in; __bf16* oh; __bf16* ol = nullptr;
  int R, C, c0, r0;
  bool lo = false;
  if (flat < 1536) {
    const int which = flat >> 9, rem = flat & 511;
    const int h = rem >> 6, tt = rem & 63;
    c0 = (tt & 7) * 32; r0 = (tt >> 3) * 32;
    const float* Wsrc = which == 0 ? Wq : which == 1 ? Wk : Wv;
    in = Wsrc + h * 65536;
    oh = Wt + which * 524288 + h * 65536;
    R = 256; C = 256;
  } else {
    const int rem = flat - 1536;
    c0 = (rem & 7) * 32; r0 = (rem >> 3) * 32;
    in = Wo; oh = Woh; ol = Wol; lo = true;
    R = 2048; C = 256;
  }
  const int tx = threadIdx.x & 31, ty = threadIdx.x >> 5;
  #pragma unroll
  for (int k = 0; k < 32; k += 8)
    t[ty + k][tx] = in[(size_t)(r0 + ty + k) * C + c0 + tx];
  __syncthreads();
  #pragma unroll
  for (int k = 0; k < 32; k += 8) {
    const float v = t[tx][ty + k];
    const size_t o = (size_t)(c0 + ty + k) * R + r0 + tx;
    const __bf16 h = (__bf16)v;
    oh[o] = h;
    if (lo) ol[o] = (__bf16)(v - (float)h);
  }
}

// ---------- QKV projection: Q+K merged per block (shared x frags), V separate ----------
__global__ __launch_bounds__(256) void k_qkv(
    const __bf16* __restrict__ xb, const __bf16* __restrict__ Wt,
    const float* __restrict__ bq, const float* __restrict__ bk, const float* __restrict__ bv,
    __bf16* __restrict__ Qb, __bf16* __restrict__ Kb, __bf16* __restrict__ Vtb) {
  const int wl = threadIdx.x >> 6, lane = threadIdx.x & 63;
  const int g = lane >> 4, qc = lane & 15;
  const int h = blockIdx.z >> 1, isV = blockIdx.z & 1;
  const int sblk = blockIdx.x * 256;
  const int s0 = sblk + wl * 64;
  const int e0 = blockIdx.y * 64;
  const int b = sblk >> 11;
  const int bh = b * 8 + h;
  const int sm0 = s0 & 2047;

  if (isV) {
    const __bf16* Wm = Wt + 2 * 524288 + (size_t)h * 65536;
    const float* bias = bv + h * 256;
    f32x4 acc[4][4] = {};
    #pragma unroll
    for (int kk = 0; kk < 8; kk++) {
      bf16x8 af[4], bf[4];
      #pragma unroll
      for (int ai = 0; ai < 4; ai++)
        af[ai] = ld8(xb + (size_t)(s0 + ai * 16 + qc) * 256 + kk * 32 + g * 8);
      #pragma unroll
      for (int bj = 0; bj < 4; bj++)
        bf[bj] = ld8(Wm + (size_t)(e0 + bj * 16 + qc) * 256 + kk * 32 + g * 8);
      #pragma unroll
      for (int ai = 0; ai < 4; ai++)
        #pragma unroll
        for (int bj = 0; bj < 4; bj++)
          acc[ai][bj] = mfma16(af[ai], bf[bj], acc[ai][bj]);
    }
    #pragma unroll
    for (int bj = 0; bj < 4; bj++) {
      const int e = e0 + bj * 16 + qc;
      const float be = bias[e];
      #pragma unroll
      for (int ai = 0; ai < 4; ai++) {
        bf16x4 pk;
        #pragma unroll
        for (int r = 0; r < 4; r++) pk[r] = (__bf16)(acc[ai][bj][r] + be);
        *reinterpret_cast<bf16x4*>(Vtb + ((size_t)(bh * 256 + e)) * 2048 +
                                   sm0 + ai * 16 + g * 4) = pk;
      }
    }
  } else {
    const __bf16* WmQ = Wt + (size_t)h * 65536;
    const __bf16* WmK = Wt + 524288 + (size_t)h * 65536;
    f32x4 accq[4][4] = {}, acck[4][4] = {};
    #pragma unroll
    for (int kk = 0; kk < 8; kk++) {
      bf16x8 aq[4], ak[4], bf[4];
      #pragma unroll
      for (int ai = 0; ai < 4; ai++) {
        aq[ai] = ld8(WmQ + (size_t)(e0 + ai * 16 + qc) * 256 + kk * 32 + g * 8);
        ak[ai] = ld8(WmK + (size_t)(e0 + ai * 16 + qc) * 256 + kk * 32 + g * 8);
      }
      #pragma unroll
      for (int bj = 0; bj < 4; bj++)
        bf[bj] = ld8(xb + (size_t)(s0 + bj * 16 + qc) * 256 + kk * 32 + g * 8);
      #pragma unroll
      for (int ai = 0; ai < 4; ai++)
        #pragma unroll
        for (int bj = 0; bj < 4; bj++) {
          accq[ai][bj] = mfma16(aq[ai], bf[bj], accq[ai][bj]);
          acck[ai][bj] = mfma16(ak[ai], bf[bj], acck[ai][bj]);
        }
    }
    // Q folds 1/sqrt(D) * log2(e)  (attention runs in exp2 domain)
    const float sc = 0.0625f * 1.4426950408889634f;
    #pragma unroll
    for (int ai = 0; ai < 4; ai++) {
      float beq[4], bek[4];
      #pragma unroll
      for (int r = 0; r < 4; r++) {
        beq[r] = bq[h * 256 + e0 + ai * 16 + g * 4 + r];
        bek[r] = bk[h * 256 + e0 + ai * 16 + g * 4 + r];
      }
      #pragma unroll
      for (int bj = 0; bj < 4; bj++) {
        const int srow = sm0 + bj * 16 + qc;
        const size_t base = ((size_t)(bh * 2048 + srow)) * 256 + e0 + ai * 16 + g * 4;
        bf16x4 pq, pk;
        #pragma unroll
        for (int r = 0; r < 4; r++) {
          pq[r] = (__bf16)((accq[ai][bj][r] + beq[r]) * sc);
          pk[r] = (__bf16)(acck[ai][bj][r] + bek[r]);
        }
        *reinterpret_cast<bf16x4*>(Qb + base) = pq;
        *reinterpret_cast<bf16x4*>(Kb + base) = pk;
      }
    }
  }
}

// ---------- flash attention (R15-proven: KVBLK=64, 128KB LDS, no setprio) ----------
__global__ __launch_bounds__(256) void k_attn(
    const __bf16* __restrict__ Qb, const __bf16* __restrict__ Kb,
    const __bf16* __restrict__ Vtb, __bf16* __restrict__ Oh, __bf16* __restrict__ Ol) {
  __shared__ __align__(16) unsigned char smem[131072];
  const int tid = threadIdx.x;
  const int wl = tid >> 6, lane = tid & 63;
  const int hi = lane >> 5, q = lane & 31;

  const int bid = blockIdx.x;
  const int s = (bid & 7) * 32 + (bid >> 3);      // XCD-chunked swizzle (bijective)
  const int bh = s >> 4, qt = s & 15;

  const int q0w = qt * 128 + wl * 32;
  const char* Kg = (const char*)Kb + ((size_t)bh * 2048) * 512;
  const char* Vg = (const char*)Vtb + (size_t)bh * 256 * 4096;
  const __bf16* Qp = Qb + ((size_t)(bh * 2048 + q0w + q)) * 256;

  bf16x8 qf[16];
  #pragma unroll
  for (int kk = 0; kk < 16; kk++) qf[kk] = ld8(Qp + kk * 16 + hi * 8);

  f32x16 acc[8];
  #pragma unroll
  for (int i = 0; i < 8; i++)
    #pragma unroll
    for (int e = 0; e < 16; e++) acc[i][e] = 0.f;

  auto stage = [&](int nb, int t) {
    unsigned char* kbp = smem + nb * 32768 + wl * 8192;
    unsigned char* vbp = smem + 65536 + nb * 32768 + wl * 8192;
    #pragma unroll
    for (int j = 0; j < 8; j++) {
      const int O = wl * 8192 + j * 1024 + lane * 16;
      const int kv = O >> 9;
      const int c = ((O >> 4) & 31) ^ (kv & 15);
      gl_lds16(Kg + (size_t)t * 32768 + (size_t)kv * 512 + c * 16, kbp + j * 1024);
    }
    #pragma unroll
    for (int j = 0; j < 8; j++) {
      const int O = wl * 8192 + j * 1024 + lane * 16;
      const int sb = O >> 10;
      const int kvh = (O >> 9) & 1;
      const int dlo = (O >> 6) & 7;
      const int ci = (O >> 4) & 3;
      const int d = sb * 8 + dlo;
      gl_lds16(Vg + (size_t)d * 4096 + (size_t)t * 128 + kvh * 64 + ((ci ^ (sb & 3)) << 4),
               vbp + j * 1024);
    }
  };

  float m_run = -3.0e38f, l_run = 0.f;
  stage(0, 0);
  __syncthreads();

  for (int t = 0; t < 32; t++) {
    const int cur = t & 1;
    const unsigned char* kbc = smem + cur * 32768;
    const unsigned char* vbc = smem + 65536 + cur * 32768;
    if (t < 31) stage(cur ^ 1, t + 1);

    // ---- QK^T (swapped): two independent 16-MFMA chains (kv rows q, 32+q) ----
    f32x16 st0, st1;
    #pragma unroll
    for (int e = 0; e < 16; e++) { st0[e] = 0.f; st1[e] = 0.f; }
    #pragma unroll
    for (int kk = 0; kk < 16; kk++) {
      const int o0 = q * 512 + ((((kk << 1) + hi) ^ (q & 15)) << 4);
      bf16x8 k0 = *reinterpret_cast<const bf16x8*>(kbc + o0);
      bf16x8 k1 = *reinterpret_cast<const bf16x8*>(kbc + o0 + 16384);
      st0 = mfma32(k0, qf[kk], st0);
      st1 = mfma32(k1, qf[kk], st1);
    }

    // ---- online softmax over 64 values, exp2 domain, defer-max THR=8 ----
    f32x16 mx;
    #pragma unroll
    for (int r = 0; r < 16; r++) mx[r] = fmaxf(st0[r], st1[r]);
    #pragma unroll
    for (int w2 = 8; w2 > 0; w2 >>= 1)
      #pragma unroll
      for (int r = 0; r < w2; r++) mx[r] = fmaxf(mx[r], mx[r + w2]);
    const float rmax = fmaxf(mx[0], __shfl_xor(mx[0], 32));
    if (__any(rmax > m_run + 8.0f)) {
      const float m_new = fmaxf(rmax, m_run);
      const float alpha = EXP2(m_run - m_new);
      m_run = m_new;
      l_run *= alpha;
      #pragma unroll
      for (int r = 0; r < 16; r++) {
        const float ar = __shfl(alpha, (r & 3) + 8 * (r >> 2) + 4 * hi);
        #pragma unroll
        for (int dt = 0; dt < 8; dt++) acc[dt][r] *= ar;
      }
    }
    f32x16 sm_;
    #pragma unroll
    for (int r = 0; r < 16; r++) {
      st0[r] = EXP2(st0[r] - m_run);
      st1[r] = EXP2(st1[r] - m_run);
      sm_[r] = st0[r] + st1[r];
    }
    #pragma unroll
    for (int w2 = 8; w2 > 0; w2 >>= 1)
      #pragma unroll
      for (int r = 0; r < w2; r++) sm_[r] += sm_[r + w2];
    l_run += sm_[0] + __shfl_xor(sm_[0], 32);

    // ---- P -> 4 PV A-frags in-register (pk2 + shfl_xor exchange) ----
    bf16x8 pa[4];
    #define MKCHUNK(STV, H2, OUT) {                          \
      const unsigned L0 = pk2(STV[H2 * 8 + 0], STV[H2 * 8 + 1]);  \
      const unsigned L1 = pk2(STV[H2 * 8 + 2], STV[H2 * 8 + 3]);  \
      const unsigned H0 = pk2(STV[H2 * 8 + 4], STV[H2 * 8 + 5]);  \
      const unsigned H1 = pk2(STV[H2 * 8 + 6], STV[H2 * 8 + 7]);  \
      const unsigned xL0 = __shfl_xor(L0, 32), xL1 = __shfl_xor(L1, 32); \
      const unsigned xH0 = __shfl_xor(H0, 32), xH1 = __shfl_xor(H1, 32); \
      unsigned pw[4];                                        \
      pw[0] = hi ? xH0 : L0;  pw[1] = hi ? xH1 : L1;         \
      pw[2] = hi ? H0 : xL0;  pw[3] = hi ? H1 : xL1;         \
      OUT = *reinterpret_cast<bf16x8*>(pw); }
    MKCHUNK(st0, 0, pa[0]); MKCHUNK(st0, 1, pa[1]);
    MKCHUNK(st1, 0, pa[2]); MKCHUNK(st1, 1, pa[3]);
    #undef MKCHUNK

    // ---- PV: acc[dt] col=d=dt*32+q ----
    #pragma unroll
    for (int dt = 0; dt < 8; dt++) {
      const int d = dt * 32 + q;
      const int base = (d >> 3) * 1024 + (d & 7) * 64;
      const int key = (d >> 3) & 3;
      #pragma unroll
      for (int c = 0; c < 4; c++) {
        const int off = base + (c >> 1) * 512 +
                        (((((c & 1) << 1) | hi) ^ key) << 4);
        bf16x8 vf = *reinterpret_cast<const bf16x8*>(vbc + off);
        acc[dt] = mfma32(pa[c], vf, acc[dt]);
      }
    }
    __syncthreads();
  }

  // ---- epilogue: divide by l, split hi/lo bf16 ----
  float linv[16];
  #pragma unroll
  for (int r = 0; r < 16; r++)
    linv[r] = 1.f / __shfl(l_run, (r & 3) + 8 * (r >> 2) + 4 * hi);
  const int b = bh >> 3, h = bh & 7;
  #pragma unroll
  for (int dt = 0; dt < 8; dt++) {
    #pragma unroll
    for (int r = 0; r < 16; r++) {
      const float v = acc[dt][r] * linv[r];
      const int qrow = (r & 3) + 8 * (r >> 2) + 4 * hi;
      const size_t off = (size_t)b * (2048 * 2048) +
                         (size_t)(q0w + qrow) * 2048 + h * 256 + dt * 32 + q;
      const __bf16 hv = (__bf16)v;
      Oh[off] = hv;
      Ol[off] = (__bf16)(v - (float)hv);
    }
  }
}

// ---------- output projection, K-split x4 + atomic accumulate ----------
__global__ __launch_bounds__(256) void k_out(
    const __bf16* __restrict__ Oh, const __bf16* __restrict__ Ol,
    const __bf16* __restrict__ Wh, const __bf16* __restrict__ Wl,
    const float* __restrict__ bo, float* __restrict__ out) {
  const int w = threadIdx.x >> 6, lane = threadIdx.x & 63;
  const int g = lane >> 4, qc = lane & 15;
  const int m0 = blockIdx.x * 64 + w * 16, n0 = blockIdx.y * 64;
  const int k0 = blockIdx.z * 512;
  f32x4 acc[4] = {};
  const __bf16* ah_p = Oh + (size_t)(m0 + qc) * 2048 + k0 + g * 8;
  const __bf16* al_p = Ol + (size_t)(m0 + qc) * 2048 + k0 + g * 8;
  for (int kk = 0; kk < 16; kk++) {
    bf16x8 ah = ld8(ah_p + kk * 32);
    bf16x8 al = ld8(al_p + kk * 32);
    #pragma unroll
    for (int nt = 0; nt < 4; nt++) {
      const size_t nrow = (size_t)(n0 + nt * 16 + qc) * 2048 + k0 + kk * 32 + g * 8;
      bf16x8 bh = ld8(Wh + nrow);
      bf16x8 bl = ld8(Wl + nrow);
      acc[nt] = mfma16(ah, bh, acc[nt]);
      acc[nt] = mfma16(al, bh, acc[nt]);
      acc[nt] = mfma16(ah, bl, acc[nt]);
    }
  }
  #pragma unroll
  for (int nt = 0; nt < 4; nt++) {
    const int n = n0 + nt * 16 + qc;
    const float bb = (blockIdx.z == 0) ? bo[n] : 0.f;
    #pragma unroll
    for (int r = 0; r < 4; r++)
      unsafeAtomicAdd(&out[(m0 + g * 4 + r) * 256 + n], acc[nt][r] + bb);
  }
}

extern "C" void kernel_launch(void* const* d_in, const int* in_sizes, int n_in,
                              void* d_out, int out_size, void* d_ws, size_t ws_size,
                              hipStream_t stream) {
  const float* x  = (const float*)d_in[0];
  const float* Wq = (const float*)d_in[1];
  const float* bq = (const float*)d_in[2];
  const float* Wk = (const float*)d_in[3];
  const float* bk = (const float*)d_in[4];
  const float* Wv = (const float*)d_in[5];
  const float* bv = (const float*)d_in[6];
  const float* Wo = (const float*)d_in[7];
  const float* bo = (const float*)d_in[8];
  char* p = (char*)d_ws;
  __bf16* xb  = (__bf16*)(p);                          // 2 MB  [4096][256]
  __bf16* Wt  = (__bf16*)(p + (2ull  << 20));          // 3 MB  [3][8][256 e][256 d]
  __bf16* Woh = (__bf16*)(p + (5ull  << 20));          // 1 MB  [256 n][2048 k]
  __bf16* Wol = (__bf16*)(p + (6ull  << 20));          // 1 MB
  __bf16* Qb  = (__bf16*)(p + (7ull  << 20));          // 16 MB [bh][s][d] (scale folded)
  __bf16* Kb  = (__bf16*)(p + (23ull << 20));          // 16 MB [bh][s][d]
  __bf16* Vtb = (__bf16*)(p + (39ull << 20));          // 16 MB [bh][d][s]
  __bf16* Ohb = (__bf16*)(p + (55ull << 20));          // 16 MB [bs][h*d] hi
  __bf16* Olb = (__bf16*)(p + (71ull << 20));          // 16 MB [bs][h*d] lo

  k_prep<<<dim3(3072), dim3(256), 0, stream>>>(x, Wq, Wk, Wv, Wo, xb, Wt, Woh, Wol);
  k_qkv<<<dim3(16, 4, 16), dim3(256), 0, stream>>>(xb, Wt, bq, bk, bv, Qb, Kb, Vtb);
  k_attn<<<dim3(256), dim3(256), 0, stream>>>(Qb, Kb, Vtb, Ohb, Olb);
  (void)hipMemsetAsync(d_out, 0, (size_t)out_size * sizeof(float), stream);
  k_out<<<dim3(64, 4, 4), dim3(256), 0, stream>>>(Ohb, Olb, Woh, Wol, bo, (float*)d_out);
}

// Round 18
// 228.174 us; speedup vs baseline: 1.3234x; 1.1024x over previous
//
#include <hip/hip_runtime.h>

typedef __bf16 bf16x8 __attribute__((ext_vector_type(8)));
typedef __bf16 bf16x4 __attribute__((ext_vector_type(4)));
typedef float  f32x4  __attribute__((ext_vector_type(4)));
typedef float  f32x16 __attribute__((ext_vector_type(16)));

#define DEVI __device__ __forceinline__

DEVI bf16x8 ld8(const __bf16* p) { return *reinterpret_cast<const bf16x8*>(p); }
DEVI f32x4 mfma16(bf16x8 a, bf16x8 b, f32x4 c) {
  return __builtin_amdgcn_mfma_f32_16x16x32_bf16(a, b, c, 0, 0, 0);
}
DEVI f32x16 mfma32(bf16x8 a, bf16x8 b, f32x16 c) {
  return __builtin_amdgcn_mfma_f32_32x32x16_bf16(a, b, c, 0, 0, 0);
}
DEVI void gl_lds16(const void* g, void* l) {
  __builtin_amdgcn_global_load_lds((__attribute__((address_space(1))) void*)g,
                                   (__attribute__((address_space(3))) void*)l, 16, 0, 0);
}
DEVI unsigned pk2(float a, float b) {
  union { __bf16 h[2]; unsigned u; } x;
  x.h[0] = (__bf16)a; x.h[1] = (__bf16)b; return x.u;
}

#if __has_builtin(__builtin_amdgcn_exp2f)
#define EXP2(x) __builtin_amdgcn_exp2f(x)
#else
#define EXP2(x) exp2f(x)
#endif

// ---------- fused prep: x cvt + Wq/Wk/Wv transpose + Wo transpose (hi only) ----------
__global__ __launch_bounds__(256) void k_prep(
    const float* __restrict__ x, const float* __restrict__ Wq,
    const float* __restrict__ Wk, const float* __restrict__ Wv,
    const float* __restrict__ Wo, __bf16* __restrict__ xb,
    __bf16* __restrict__ Wt, __bf16* __restrict__ Woh, __bf16* __restrict__ Wol) {
  const int bid = blockIdx.x;
  if (bid < 1024) {
    const int i = bid * 256 + threadIdx.x;
    f32x4 v = reinterpret_cast<const f32x4*>(x)[i];
    bf16x4 o;
    o[0] = (__bf16)v[0]; o[1] = (__bf16)v[1]; o[2] = (__bf16)v[2]; o[3] = (__bf16)v[3];
    reinterpret_cast<bf16x4*>(xb)[i] = o;
    return;
  }
  __shared__ float t[32][33];
  const int flat = bid - 1024;
  const float* in; __bf16* oh; __bf16* ol = nullptr;
  int R, C, c0, r0;
  bool lo = false;
  if (flat < 1536) {
    const int which = flat >> 9, rem = flat & 511;
    const int h = rem >> 6, tt = rem & 63;
    c0 = (tt & 7) * 32; r0 = (tt >> 3) * 32;
    const float* Wsrc = which == 0 ? Wq : which == 1 ? Wk : Wv;
    in = Wsrc + h * 65536;
    oh = Wt + which * 524288 + h * 65536;
    R = 256; C = 256;
  } else {
    const int rem = flat - 1536;
    c0 = (rem & 7) * 32; r0 = (rem >> 3) * 32;
    in = Wo; oh = Woh; ol = Wol; lo = true;
    R = 2048; C = 256;
  }
  const int tx = threadIdx.x & 31, ty = threadIdx.x >> 5;
  #pragma unroll
  for (int k = 0; k < 32; k += 8)
    t[ty + k][tx] = in[(size_t)(r0 + ty + k) * C + c0 + tx];
  __syncthreads();
  #pragma unroll
  for (int k = 0; k < 32; k += 8) {
    const float v = t[tx][ty + k];
    const size_t o = (size_t)(c0 + ty + k) * R + r0 + tx;
    const __bf16 h = (__bf16)v;
    oh[o] = h;
    if (lo) ol[o] = (__bf16)(v - (float)h);
  }
}

// ---------- QKV projection: Q+K merged per block (shared x frags), V separate ----------
__global__ __launch_bounds__(256) void k_qkv(
    const __bf16* __restrict__ xb, const __bf16* __restrict__ Wt,
    const float* __restrict__ bq, const float* __restrict__ bk, const float* __restrict__ bv,
    __bf16* __restrict__ Qb, __bf16* __restrict__ Kb, __bf16* __restrict__ Vtb) {
  const int wl = threadIdx.x >> 6, lane = threadIdx.x & 63;
  const int g = lane >> 4, qc = lane & 15;
  const int h = blockIdx.z >> 1, isV = blockIdx.z & 1;
  const int sblk = blockIdx.x * 256;
  const int s0 = sblk + wl * 64;
  const int e0 = blockIdx.y * 64;
  const int b = sblk >> 11;
  const int bh = b * 8 + h;
  const int sm0 = s0 & 2047;

  if (isV) {
    const __bf16* Wm = Wt + 2 * 524288 + (size_t)h * 65536;
    const float* bias = bv + h * 256;
    f32x4 acc[4][4] = {};
    #pragma unroll
    for (int kk = 0; kk < 8; kk++) {
      bf16x8 af[4], bf[4];
      #pragma unroll
      for (int ai = 0; ai < 4; ai++)
        af[ai] = ld8(xb + (size_t)(s0 + ai * 16 + qc) * 256 + kk * 32 + g * 8);
      #pragma unroll
      for (int bj = 0; bj < 4; bj++)
        bf[bj] = ld8(Wm + (size_t)(e0 + bj * 16 + qc) * 256 + kk * 32 + g * 8);
      #pragma unroll
      for (int ai = 0; ai < 4; ai++)
        #pragma unroll
        for (int bj = 0; bj < 4; bj++)
          acc[ai][bj] = mfma16(af[ai], bf[bj], acc[ai][bj]);
    }
    #pragma unroll
    for (int bj = 0; bj < 4; bj++) {
      const int e = e0 + bj * 16 + qc;
      const float be = bias[e];
      #pragma unroll
      for (int ai = 0; ai < 4; ai++) {
        bf16x4 pk;
        #pragma unroll
        for (int r = 0; r < 4; r++) pk[r] = (__bf16)(acc[ai][bj][r] + be);
        *reinterpret_cast<bf16x4*>(Vtb + ((size_t)(bh * 256 + e)) * 2048 +
                                   sm0 + ai * 16 + g * 4) = pk;
      }
    }
  } else {
    const __bf16* WmQ = Wt + (size_t)h * 65536;
    const __bf16* WmK = Wt + 524288 + (size_t)h * 65536;
    f32x4 accq[4][4] = {}, acck[4][4] = {};
    #pragma unroll
    for (int kk = 0; kk < 8; kk++) {
      bf16x8 aq[4], ak[4], bf[4];
      #pragma unroll
      for (int ai = 0; ai < 4; ai++) {
        aq[ai] = ld8(WmQ + (size_t)(e0 + ai * 16 + qc) * 256 + kk * 32 + g * 8);
        ak[ai] = ld8(WmK + (size_t)(e0 + ai * 16 + qc) * 256 + kk * 32 + g * 8);
      }
      #pragma unroll
      for (int bj = 0; bj < 4; bj++)
        bf[bj] = ld8(xb + (size_t)(s0 + bj * 16 + qc) * 256 + kk * 32 + g * 8);
      #pragma unroll
      for (int ai = 0; ai < 4; ai++)
        #pragma unroll
        for (int bj = 0; bj < 4; bj++) {
          accq[ai][bj] = mfma16(aq[ai], bf[bj], accq[ai][bj]);
          acck[ai][bj] = mfma16(ak[ai], bf[bj], acck[ai][bj]);
        }
    }
    // Q folds 1/sqrt(D) * log2(e)  (attention runs in exp2 domain)
    const float sc = 0.0625f * 1.4426950408889634f;
    #pragma unroll
    for (int ai = 0; ai < 4; ai++) {
      float beq[4], bek[4];
      #pragma unroll
      for (int r = 0; r < 4; r++) {
        beq[r] = bq[h * 256 + e0 + ai * 16 + g * 4 + r];
        bek[r] = bk[h * 256 + e0 + ai * 16 + g * 4 + r];
      }
      #pragma unroll
      for (int bj = 0; bj < 4; bj++) {
        const int srow = sm0 + bj * 16 + qc;
        const size_t base = ((size_t)(bh * 2048 + srow)) * 256 + e0 + ai * 16 + g * 4;
        bf16x4 pq, pk;
        #pragma unroll
        for (int r = 0; r < 4; r++) {
          pq[r] = (__bf16)((accq[ai][bj][r] + beq[r]) * sc);
          pk[r] = (__bf16)(acck[ai][bj][r] + bek[r]);
        }
        *reinterpret_cast<bf16x4*>(Qb + base) = pq;
        *reinterpret_cast<bf16x4*>(Kb + base) = pk;
      }
    }
  }
}

// ---------- flash attention (R15/R17-proven: KVBLK=64, 128KB LDS, no setprio) ----------
__global__ __launch_bounds__(256) void k_attn(
    const __bf16* __restrict__ Qb, const __bf16* __restrict__ Kb,
    const __bf16* __restrict__ Vtb, __bf16* __restrict__ Oh, __bf16* __restrict__ Ol) {
  __shared__ __align__(16) unsigned char smem[131072];
  const int tid = threadIdx.x;
  const int wl = tid >> 6, lane = tid & 63;
  const int hi = lane >> 5, q = lane & 31;

  const int bid = blockIdx.x;
  const int s = (bid & 7) * 32 + (bid >> 3);      // XCD-chunked swizzle (bijective)
  const int bh = s >> 4, qt = s & 15;

  const int q0w = qt * 128 + wl * 32;
  const char* Kg = (const char*)Kb + ((size_t)bh * 2048) * 512;
  const char* Vg = (const char*)Vtb + (size_t)bh * 256 * 4096;
  const __bf16* Qp = Qb + ((size_t)(bh * 2048 + q0w + q)) * 256;

  bf16x8 qf[16];
  #pragma unroll
  for (int kk = 0; kk < 16; kk++) qf[kk] = ld8(Qp + kk * 16 + hi * 8);

  f32x16 acc[8];
  #pragma unroll
  for (int i = 0; i < 8; i++)
    #pragma unroll
    for (int e = 0; e < 16; e++) acc[i][e] = 0.f;

  auto stage = [&](int nb, int t) {
    unsigned char* kbp = smem + nb * 32768 + wl * 8192;
    unsigned char* vbp = smem + 65536 + nb * 32768 + wl * 8192;
    #pragma unroll
    for (int j = 0; j < 8; j++) {
      const int O = wl * 8192 + j * 1024 + lane * 16;
      const int kv = O >> 9;
      const int c = ((O >> 4) & 31) ^ (kv & 15);
      gl_lds16(Kg + (size_t)t * 32768 + (size_t)kv * 512 + c * 16, kbp + j * 1024);
    }
    #pragma unroll
    for (int j = 0; j < 8; j++) {
      const int O = wl * 8192 + j * 1024 + lane * 16;
      const int sb = O >> 10;
      const int kvh = (O >> 9) & 1;
      const int dlo = (O >> 6) & 7;
      const int ci = (O >> 4) & 3;
      const int d = sb * 8 + dlo;
      gl_lds16(Vg + (size_t)d * 4096 + (size_t)t * 128 + kvh * 64 + ((ci ^ (sb & 3)) << 4),
               vbp + j * 1024);
    }
  };

  float m_run = -3.0e38f, l_run = 0.f;
  stage(0, 0);
  __syncthreads();

  for (int t = 0; t < 32; t++) {
    const int cur = t & 1;
    const unsigned char* kbc = smem + cur * 32768;
    const unsigned char* vbc = smem + 65536 + cur * 32768;
    if (t < 31) stage(cur ^ 1, t + 1);

    // ---- QK^T (swapped): two independent 16-MFMA chains (kv rows q, 32+q) ----
    f32x16 st0, st1;
    #pragma unroll
    for (int e = 0; e < 16; e++) { st0[e] = 0.f; st1[e] = 0.f; }
    #pragma unroll
    for (int kk = 0; kk < 16; kk++) {
      const int o0 = q * 512 + ((((kk << 1) + hi) ^ (q & 15)) << 4);
      bf16x8 k0 = *reinterpret_cast<const bf16x8*>(kbc + o0);
      bf16x8 k1 = *reinterpret_cast<const bf16x8*>(kbc + o0 + 16384);
      st0 = mfma32(k0, qf[kk], st0);
      st1 = mfma32(k1, qf[kk], st1);
    }

    // ---- online softmax over 64 values, exp2 domain, defer-max THR=8 ----
    f32x16 mx;
    #pragma unroll
    for (int r = 0; r < 16; r++) mx[r] = fmaxf(st0[r], st1[r]);
    #pragma unroll
    for (int w2 = 8; w2 > 0; w2 >>= 1)
      #pragma unroll
      for (int r = 0; r < w2; r++) mx[r] = fmaxf(mx[r], mx[r + w2]);
    const float rmax = fmaxf(mx[0], __shfl_xor(mx[0], 32));
    if (__any(rmax > m_run + 8.0f)) {
      const float m_new = fmaxf(rmax, m_run);
      const float alpha = EXP2(m_run - m_new);
      m_run = m_new;
      l_run *= alpha;
      #pragma unroll
      for (int r = 0; r < 16; r++) {
        const float ar = __shfl(alpha, (r & 3) + 8 * (r >> 2) + 4 * hi);
        #pragma unroll
        for (int dt = 0; dt < 8; dt++) acc[dt][r] *= ar;
      }
    }
    f32x16 sm_;
    #pragma unroll
    for (int r = 0; r < 16; r++) {
      st0[r] = EXP2(st0[r] - m_run);
      st1[r] = EXP2(st1[r] - m_run);
      sm_[r] = st0[r] + st1[r];
    }
    #pragma unroll
    for (int w2 = 8; w2 > 0; w2 >>= 1)
      #pragma unroll
      for (int r = 0; r < w2; r++) sm_[r] += sm_[r + w2];
    l_run += sm_[0] + __shfl_xor(sm_[0], 32);

    // ---- P -> 4 PV A-frags in-register (pk2 + shfl_xor exchange) ----
    bf16x8 pa[4];
    #define MKCHUNK(STV, H2, OUT) {                          \
      const unsigned L0 = pk2(STV[H2 * 8 + 0], STV[H2 * 8 + 1]);  \
      const unsigned L1 = pk2(STV[H2 * 8 + 2], STV[H2 * 8 + 3]);  \
      const unsigned H0 = pk2(STV[H2 * 8 + 4], STV[H2 * 8 + 5]);  \
      const unsigned H1 = pk2(STV[H2 * 8 + 6], STV[H2 * 8 + 7]);  \
      const unsigned xL0 = __shfl_xor(L0, 32), xL1 = __shfl_xor(L1, 32); \
      const unsigned xH0 = __shfl_xor(H0, 32), xH1 = __shfl_xor(H1, 32); \
      unsigned pw[4];                                        \
      pw[0] = hi ? xH0 : L0;  pw[1] = hi ? xH1 : L1;         \
      pw[2] = hi ? H0 : xL0;  pw[3] = hi ? H1 : xL1;         \
      OUT = *reinterpret_cast<bf16x8*>(pw); }
    MKCHUNK(st0, 0, pa[0]); MKCHUNK(st0, 1, pa[1]);
    MKCHUNK(st1, 0, pa[2]); MKCHUNK(st1, 1, pa[3]);
    #undef MKCHUNK

    // ---- PV: acc[dt] col=d=dt*32+q ----
    #pragma unroll
    for (int dt = 0; dt < 8; dt++) {
      const int d = dt * 32 + q;
      const int base = (d >> 3) * 1024 + (d & 7) * 64;
      const int key = (d >> 3) & 3;
      #pragma unroll
      for (int c = 0; c < 4; c++) {
        const int off = base + (c >> 1) * 512 +
                        (((((c & 1) << 1) | hi) ^ key) << 4);
        bf16x8 vf = *reinterpret_cast<const bf16x8*>(vbc + off);
        acc[dt] = mfma32(pa[c], vf, acc[dt]);
      }
    }
    __syncthreads();
  }

  // ---- epilogue: divide by l, split hi/lo bf16 ----
  float linv[16];
  #pragma unroll
  for (int r = 0; r < 16; r++)
    linv[r] = 1.f / __shfl(l_run, (r & 3) + 8 * (r >> 2) + 4 * hi);
  const int b = bh >> 3, h = bh & 7;
  #pragma unroll
  for (int dt = 0; dt < 8; dt++) {
    #pragma unroll
    for (int r = 0; r < 16; r++) {
      const float v = acc[dt][r] * linv[r];
      const int qrow = (r & 3) + 8 * (r >> 2) + 4 * hi;
      const size_t off = (size_t)b * (2048 * 2048) +
                         (size_t)(q0w + qrow) * 2048 + h * 256 + dt * 32 + q;
      const __bf16 hv = (__bf16)v;
      Oh[off] = hv;
      Ol[off] = (__bf16)(v - (float)hv);
    }
  }
}

// ---------- output projection, K-split x4, 2-term split (Wl term dropped) ----------
// Error budget: dropping Wl*Oh adds ~1e-3 RMS; measured absmax was 1.95e-3 of
// 7.58e-3 threshold -> predicted ~3e-3 total. Saves 1/3 of MFMAs + 1/4 of loads.
__global__ __launch_bounds__(256) void k_out(
    const __bf16* __restrict__ Oh, const __bf16* __restrict__ Ol,
    const __bf16* __restrict__ Wh,
    const float* __restrict__ bo, float* __restrict__ out) {
  const int w = threadIdx.x >> 6, lane = threadIdx.x & 63;
  const int g = lane >> 4, qc = lane & 15;
  const int m0 = blockIdx.x * 64 + w * 16, n0 = blockIdx.y * 64;
  const int k0 = blockIdx.z * 512;
  f32x4 acc[4] = {};
  const __bf16* ah_p = Oh + (size_t)(m0 + qc) * 2048 + k0 + g * 8;
  const __bf16* al_p = Ol + (size_t)(m0 + qc) * 2048 + k0 + g * 8;
  for (int kk = 0; kk < 16; kk++) {
    bf16x8 ah = ld8(ah_p + kk * 32);
    bf16x8 al = ld8(al_p + kk * 32);
    #pragma unroll
    for (int nt = 0; nt < 4; nt++) {
      const size_t nrow = (size_t)(n0 + nt * 16 + qc) * 2048 + k0 + kk * 32 + g * 8;
      bf16x8 bh = ld8(Wh + nrow);
      acc[nt] = mfma16(ah, bh, acc[nt]);
      acc[nt] = mfma16(al, bh, acc[nt]);
    }
  }
  #pragma unroll
  for (int nt = 0; nt < 4; nt++) {
    const int n = n0 + nt * 16 + qc;
    const float bb = (blockIdx.z == 0) ? bo[n] : 0.f;
    #pragma unroll
    for (int r = 0; r < 4; r++)
      unsafeAtomicAdd(&out[(m0 + g * 4 + r) * 256 + n], acc[nt][r] + bb);
  }
}

extern "C" void kernel_launch(void* const* d_in, const int* in_sizes, int n_in,
                              void* d_out, int out_size, void* d_ws, size_t ws_size,
                              hipStream_t stream) {
  const float* x  = (const float*)d_in[0];
  const float* Wq = (const float*)d_in[1];
  const float* bq = (const float*)d_in[2];
  const float* Wk = (const float*)d_in[3];
  const float* bk = (const float*)d_in[4];
  const float* Wv = (const float*)d_in[5];
  const float* bv = (const float*)d_in[6];
  const float* Wo = (const float*)d_in[7];
  const float* bo = (const float*)d_in[8];
  char* p = (char*)d_ws;
  __bf16* xb  = (__bf16*)(p);                          // 2 MB  [4096][256]
  __bf16* Wt  = (__bf16*)(p + (2ull  << 20));          // 3 MB  [3][8][256 e][256 d]
  __bf16* Woh = (__bf16*)(p + (5ull  << 20));          // 1 MB  [256 n][2048 k]
  __bf16* Wol = (__bf16*)(p + (6ull  << 20));          // 1 MB  (written, unused)
  __bf16* Qb  = (__bf16*)(p + (7ull  << 20));          // 16 MB [bh][s][d] (scale folded)
  __bf16* Kb  = (__bf16*)(p + (23ull << 20));          // 16 MB [bh][s][d]
  __bf16* Vtb = (__bf16*)(p + (39ull << 20));          // 16 MB [bh][d][s]
  __bf16* Ohb = (__bf16*)(p + (55ull << 20));          // 16 MB [bs][h*d] hi
  __bf16* Olb = (__bf16*)(p + (71ull << 20));          // 16 MB [bs][h*d] lo

  k_prep<<<dim3(3072), dim3(256), 0, stream>>>(x, Wq, Wk, Wv, Wo, xb, Wt, Woh, Wol);
  k_qkv<<<dim3(16, 4, 16), dim3(256), 0, stream>>>(xb, Wt, bq, bk, bv, Qb, Kb, Vtb);
  k_attn<<<dim3(256), dim3(256), 0, stream>>>(Qb, Kb, Vtb, Ohb, Olb);
  (void)hipMemsetAsync(d_out, 0, (size_t)out_size * sizeof(float), stream);
  k_out<<<dim3(64, 4, 4), dim3(256), 0, stream>>>(Ohb, Olb, Woh, bo, (float*)d_out);
}

// Round 19
// 215.872 us; speedup vs baseline: 1.3988x; 1.0570x over previous
//
#include <hip/hip_runtime.h>

typedef __bf16 bf16x8 __attribute__((ext_vector_type(8)));
typedef __bf16 bf16x4 __attribute__((ext_vector_type(4)));
typedef float  f32x4  __attribute__((ext_vector_type(4)));
typedef float  f32x16 __attribute__((ext_vector_type(16)));

#define DEVI __device__ __forceinline__

DEVI bf16x8 ld8(const __bf16* p) { return *reinterpret_cast<const bf16x8*>(p); }
DEVI f32x4 mfma16(bf16x8 a, bf16x8 b, f32x4 c) {
  return __builtin_amdgcn_mfma_f32_16x16x32_bf16(a, b, c, 0, 0, 0);
}
DEVI f32x16 mfma32(bf16x8 a, bf16x8 b, f32x16 c) {
  return __builtin_amdgcn_mfma_f32_32x32x16_bf16(a, b, c, 0, 0, 0);
}
DEVI void gl_lds16(const void* g, void* l) {
  __builtin_amdgcn_global_load_lds((__attribute__((address_space(1))) void*)g,
                                   (__attribute__((address_space(3))) void*)l, 16, 0, 0);
}
DEVI unsigned pk2(float a, float b) {
  union { __bf16 h[2]; unsigned u; } x;
  x.h[0] = (__bf16)a; x.h[1] = (__bf16)b; return x.u;
}

#if __has_builtin(__builtin_amdgcn_exp2f)
#define EXP2(x) __builtin_amdgcn_exp2f(x)
#else
#define EXP2(x) exp2f(x)
#endif

// ---------- fused prep: x cvt + Wq/Wk/Wv transpose + Wo transpose (hi only) ----------
__global__ __launch_bounds__(256) void k_prep(
    const float* __restrict__ x, const float* __restrict__ Wq,
    const float* __restrict__ Wk, const float* __restrict__ Wv,
    const float* __restrict__ Wo, __bf16* __restrict__ xb,
    __bf16* __restrict__ Wt, __bf16* __restrict__ Woh) {
  const int bid = blockIdx.x;
  if (bid < 1024) {
    const int i = bid * 256 + threadIdx.x;
    f32x4 v = reinterpret_cast<const f32x4*>(x)[i];
    bf16x4 o;
    o[0] = (__bf16)v[0]; o[1] = (__bf16)v[1]; o[2] = (__bf16)v[2]; o[3] = (__bf16)v[3];
    reinterpret_cast<bf16x4*>(xb)[i] = o;
    return;
  }
  __shared__ float t[32][33];
  const int flat = bid - 1024;
  const float* in; __bf16* oh;
  int R, C, c0, r0;
  if (flat < 1536) {
    const int which = flat >> 9, rem = flat & 511;
    const int h = rem >> 6, tt = rem & 63;
    c0 = (tt & 7) * 32; r0 = (tt >> 3) * 32;
    const float* Wsrc = which == 0 ? Wq : which == 1 ? Wk : Wv;
    in = Wsrc + h * 65536;
    oh = Wt + which * 524288 + h * 65536;
    R = 256; C = 256;
  } else {
    const int rem = flat - 1536;
    c0 = (rem & 7) * 32; r0 = (rem >> 3) * 32;
    in = Wo; oh = Woh;
    R = 2048; C = 256;
  }
  const int tx = threadIdx.x & 31, ty = threadIdx.x >> 5;
  #pragma unroll
  for (int k = 0; k < 32; k += 8)
    t[ty + k][tx] = in[(size_t)(r0 + ty + k) * C + c0 + tx];
  __syncthreads();
  #pragma unroll
  for (int k = 0; k < 32; k += 8) {
    const float v = t[tx][ty + k];
    const size_t o = (size_t)(c0 + ty + k) * R + r0 + tx;
    oh[o] = (__bf16)v;
  }
}

// ---------- QKV projection: Q+K merged per block (shared x frags), V separate ----------
__global__ __launch_bounds__(256) void k_qkv(
    const __bf16* __restrict__ xb, const __bf16* __restrict__ Wt,
    const float* __restrict__ bq, const float* __restrict__ bk, const float* __restrict__ bv,
    __bf16* __restrict__ Qb, __bf16* __restrict__ Kb, __bf16* __restrict__ Vtb) {
  const int wl = threadIdx.x >> 6, lane = threadIdx.x & 63;
  const int g = lane >> 4, qc = lane & 15;
  const int h = blockIdx.z >> 1, isV = blockIdx.z & 1;
  const int sblk = blockIdx.x * 256;
  const int s0 = sblk + wl * 64;
  const int e0 = blockIdx.y * 64;
  const int b = sblk >> 11;
  const int bh = b * 8 + h;
  const int sm0 = s0 & 2047;

  if (isV) {
    const __bf16* Wm = Wt + 2 * 524288 + (size_t)h * 65536;
    const float* bias = bv + h * 256;
    f32x4 acc[4][4] = {};
    #pragma unroll
    for (int kk = 0; kk < 8; kk++) {
      bf16x8 af[4], bf[4];
      #pragma unroll
      for (int ai = 0; ai < 4; ai++)
        af[ai] = ld8(xb + (size_t)(s0 + ai * 16 + qc) * 256 + kk * 32 + g * 8);
      #pragma unroll
      for (int bj = 0; bj < 4; bj++)
        bf[bj] = ld8(Wm + (size_t)(e0 + bj * 16 + qc) * 256 + kk * 32 + g * 8);
      #pragma unroll
      for (int ai = 0; ai < 4; ai++)
        #pragma unroll
        for (int bj = 0; bj < 4; bj++)
          acc[ai][bj] = mfma16(af[ai], bf[bj], acc[ai][bj]);
    }
    #pragma unroll
    for (int bj = 0; bj < 4; bj++) {
      const int e = e0 + bj * 16 + qc;
      const float be = bias[e];
      #pragma unroll
      for (int ai = 0; ai < 4; ai++) {
        bf16x4 pk;
        #pragma unroll
        for (int r = 0; r < 4; r++) pk[r] = (__bf16)(acc[ai][bj][r] + be);
        *reinterpret_cast<bf16x4*>(Vtb + ((size_t)(bh * 256 + e)) * 2048 +
                                   sm0 + ai * 16 + g * 4) = pk;
      }
    }
  } else {
    const __bf16* WmQ = Wt + (size_t)h * 65536;
    const __bf16* WmK = Wt + 524288 + (size_t)h * 65536;
    f32x4 accq[4][4] = {}, acck[4][4] = {};
    #pragma unroll
    for (int kk = 0; kk < 8; kk++) {
      bf16x8 aq[4], ak[4], bf[4];
      #pragma unroll
      for (int ai = 0; ai < 4; ai++) {
        aq[ai] = ld8(WmQ + (size_t)(e0 + ai * 16 + qc) * 256 + kk * 32 + g * 8);
        ak[ai] = ld8(WmK + (size_t)(e0 + ai * 16 + qc) * 256 + kk * 32 + g * 8);
      }
      #pragma unroll
      for (int bj = 0; bj < 4; bj++)
        bf[bj] = ld8(xb + (size_t)(s0 + bj * 16 + qc) * 256 + kk * 32 + g * 8);
      #pragma unroll
      for (int ai = 0; ai < 4; ai++)
        #pragma unroll
        for (int bj = 0; bj < 4; bj++) {
          accq[ai][bj] = mfma16(aq[ai], bf[bj], accq[ai][bj]);
          acck[ai][bj] = mfma16(ak[ai], bf[bj], acck[ai][bj]);
        }
    }
    // Q folds 1/sqrt(D) * log2(e)  (attention runs in exp2 domain)
    const float sc = 0.0625f * 1.4426950408889634f;
    #pragma unroll
    for (int ai = 0; ai < 4; ai++) {
      float beq[4], bek[4];
      #pragma unroll
      for (int r = 0; r < 4; r++) {
        beq[r] = bq[h * 256 + e0 + ai * 16 + g * 4 + r];
        bek[r] = bk[h * 256 + e0 + ai * 16 + g * 4 + r];
      }
      #pragma unroll
      for (int bj = 0; bj < 4; bj++) {
        const int srow = sm0 + bj * 16 + qc;
        const size_t base = ((size_t)(bh * 2048 + srow)) * 256 + e0 + ai * 16 + g * 4;
        bf16x4 pq, pk;
        #pragma unroll
        for (int r = 0; r < 4; r++) {
          pq[r] = (__bf16)((accq[ai][bj][r] + beq[r]) * sc);
          pk[r] = (__bf16)(acck[ai][bj][r] + bek[r]);
        }
        *reinterpret_cast<bf16x4*>(Qb + base) = pq;
        *reinterpret_cast<bf16x4*>(Kb + base) = pk;
      }
    }
  }
}

// ---------- flash attention (R15/R17-proven; epilogue writes Oh only) ----------
__global__ __launch_bounds__(256) void k_attn(
    const __bf16* __restrict__ Qb, const __bf16* __restrict__ Kb,
    const __bf16* __restrict__ Vtb, __bf16* __restrict__ Oh) {
  __shared__ __align__(16) unsigned char smem[131072];
  const int tid = threadIdx.x;
  const int wl = tid >> 6, lane = tid & 63;
  const int hi = lane >> 5, q = lane & 31;

  const int bid = blockIdx.x;
  const int s = (bid & 7) * 32 + (bid >> 3);      // XCD-chunked swizzle (bijective)
  const int bh = s >> 4, qt = s & 15;

  const int q0w = qt * 128 + wl * 32;
  const char* Kg = (const char*)Kb + ((size_t)bh * 2048) * 512;
  const char* Vg = (const char*)Vtb + (size_t)bh * 256 * 4096;
  const __bf16* Qp = Qb + ((size_t)(bh * 2048 + q0w + q)) * 256;

  bf16x8 qf[16];
  #pragma unroll
  for (int kk = 0; kk < 16; kk++) qf[kk] = ld8(Qp + kk * 16 + hi * 8);

  f32x16 acc[8];
  #pragma unroll
  for (int i = 0; i < 8; i++)
    #pragma unroll
    for (int e = 0; e < 16; e++) acc[i][e] = 0.f;

  auto stage = [&](int nb, int t) {
    unsigned char* kbp = smem + nb * 32768 + wl * 8192;
    unsigned char* vbp = smem + 65536 + nb * 32768 + wl * 8192;
    #pragma unroll
    for (int j = 0; j < 8; j++) {
      const int O = wl * 8192 + j * 1024 + lane * 16;
      const int kv = O >> 9;
      const int c = ((O >> 4) & 31) ^ (kv & 15);
      gl_lds16(Kg + (size_t)t * 32768 + (size_t)kv * 512 + c * 16, kbp + j * 1024);
    }
    #pragma unroll
    for (int j = 0; j < 8; j++) {
      const int O = wl * 8192 + j * 1024 + lane * 16;
      const int sb = O >> 10;
      const int kvh = (O >> 9) & 1;
      const int dlo = (O >> 6) & 7;
      const int ci = (O >> 4) & 3;
      const int d = sb * 8 + dlo;
      gl_lds16(Vg + (size_t)d * 4096 + (size_t)t * 128 + kvh * 64 + ((ci ^ (sb & 3)) << 4),
               vbp + j * 1024);
    }
  };

  float m_run = -3.0e38f, l_run = 0.f;
  stage(0, 0);
  __syncthreads();

  for (int t = 0; t < 32; t++) {
    const int cur = t & 1;
    const unsigned char* kbc = smem + cur * 32768;
    const unsigned char* vbc = smem + 65536 + cur * 32768;
    if (t < 31) stage(cur ^ 1, t + 1);

    // ---- QK^T (swapped): two independent 16-MFMA chains (kv rows q, 32+q) ----
    f32x16 st0, st1;
    #pragma unroll
    for (int e = 0; e < 16; e++) { st0[e] = 0.f; st1[e] = 0.f; }
    #pragma unroll
    for (int kk = 0; kk < 16; kk++) {
      const int o0 = q * 512 + ((((kk << 1) + hi) ^ (q & 15)) << 4);
      bf16x8 k0 = *reinterpret_cast<const bf16x8*>(kbc + o0);
      bf16x8 k1 = *reinterpret_cast<const bf16x8*>(kbc + o0 + 16384);
      st0 = mfma32(k0, qf[kk], st0);
      st1 = mfma32(k1, qf[kk], st1);
    }

    // ---- online softmax over 64 values, exp2 domain, defer-max THR=8 ----
    f32x16 mx;
    #pragma unroll
    for (int r = 0; r < 16; r++) mx[r] = fmaxf(st0[r], st1[r]);
    #pragma unroll
    for (int w2 = 8; w2 > 0; w2 >>= 1)
      #pragma unroll
      for (int r = 0; r < w2; r++) mx[r] = fmaxf(mx[r], mx[r + w2]);
    const float rmax = fmaxf(mx[0], __shfl_xor(mx[0], 32));
    if (__any(rmax > m_run + 8.0f)) {
      const float m_new = fmaxf(rmax, m_run);
      const float alpha = EXP2(m_run - m_new);
      m_run = m_new;
      l_run *= alpha;
      #pragma unroll
      for (int r = 0; r < 16; r++) {
        const float ar = __shfl(alpha, (r & 3) + 8 * (r >> 2) + 4 * hi);
        #pragma unroll
        for (int dt = 0; dt < 8; dt++) acc[dt][r] *= ar;
      }
    }
    f32x16 sm_;
    #pragma unroll
    for (int r = 0; r < 16; r++) {
      st0[r] = EXP2(st0[r] - m_run);
      st1[r] = EXP2(st1[r] - m_run);
      sm_[r] = st0[r] + st1[r];
    }
    #pragma unroll
    for (int w2 = 8; w2 > 0; w2 >>= 1)
      #pragma unroll
      for (int r = 0; r < w2; r++) sm_[r] += sm_[r + w2];
    l_run += sm_[0] + __shfl_xor(sm_[0], 32);

    // ---- P -> 4 PV A-frags in-register (pk2 + shfl_xor exchange) ----
    bf16x8 pa[4];
    #define MKCHUNK(STV, H2, OUT) {                          \
      const unsigned L0 = pk2(STV[H2 * 8 + 0], STV[H2 * 8 + 1]);  \
      const unsigned L1 = pk2(STV[H2 * 8 + 2], STV[H2 * 8 + 3]);  \
      const unsigned H0 = pk2(STV[H2 * 8 + 4], STV[H2 * 8 + 5]);  \
      const unsigned H1 = pk2(STV[H2 * 8 + 6], STV[H2 * 8 + 7]);  \
      const unsigned xL0 = __shfl_xor(L0, 32), xL1 = __shfl_xor(L1, 32); \
      const unsigned xH0 = __shfl_xor(H0, 32), xH1 = __shfl_xor(H1, 32); \
      unsigned pw[4];                                        \
      pw[0] = hi ? xH0 : L0;  pw[1] = hi ? xH1 : L1;         \
      pw[2] = hi ? H0 : xL0;  pw[3] = hi ? H1 : xL1;         \
      OUT = *reinterpret_cast<bf16x8*>(pw); }
    MKCHUNK(st0, 0, pa[0]); MKCHUNK(st0, 1, pa[1]);
    MKCHUNK(st1, 0, pa[2]); MKCHUNK(st1, 1, pa[3]);
    #undef MKCHUNK

    // ---- PV: acc[dt] col=d=dt*32+q ----
    #pragma unroll
    for (int dt = 0; dt < 8; dt++) {
      const int d = dt * 32 + q;
      const int base = (d >> 3) * 1024 + (d & 7) * 64;
      const int key = (d >> 3) & 3;
      #pragma unroll
      for (int c = 0; c < 4; c++) {
        const int off = base + (c >> 1) * 512 +
                        (((((c & 1) << 1) | hi) ^ key) << 4);
        bf16x8 vf = *reinterpret_cast<const bf16x8*>(vbc + off);
        acc[dt] = mfma32(pa[c], vf, acc[dt]);
      }
    }
    __syncthreads();
  }

  // ---- epilogue: divide by l, bf16 round (single output; Ol dropped) ----
  float linv[16];
  #pragma unroll
  for (int r = 0; r < 16; r++)
    linv[r] = 1.f / __shfl(l_run, (r & 3) + 8 * (r >> 2) + 4 * hi);
  const int b = bh >> 3, h = bh & 7;
  #pragma unroll
  for (int dt = 0; dt < 8; dt++) {
    #pragma unroll
    for (int r = 0; r < 16; r++) {
      const float v = acc[dt][r] * linv[r];
      const int qrow = (r & 3) + 8 * (r >> 2) + 4 * hi;
      const size_t off = (size_t)b * (2048 * 2048) +
                         (size_t)(q0w + qrow) * 2048 + h * 256 + dt * 32 + q;
      Oh[off] = (__bf16)v;
    }
  }
}

// ---------- output projection, K-split x4, single term Wh*Oh ----------
// Error budget: Wl term (R18) was below output quantization (absmax unchanged);
// Ol term contributes ~0.6 ulp RMS -> total predicted 2-4 ulps vs 8-ulp threshold.
__global__ __launch_bounds__(256) void k_out(
    const __bf16* __restrict__ Oh, const __bf16* __restrict__ Wh,
    const float* __restrict__ bo, float* __restrict__ out) {
  const int w = threadIdx.x >> 6, lane = threadIdx.x & 63;
  const int g = lane >> 4, qc = lane & 15;
  const int m0 = blockIdx.x * 64 + w * 16, n0 = blockIdx.y * 64;
  const int k0 = blockIdx.z * 512;
  f32x4 acc[4] = {};
  const __bf16* ah_p = Oh + (size_t)(m0 + qc) * 2048 + k0 + g * 8;
  for (int kk = 0; kk < 16; kk++) {
    bf16x8 ah = ld8(ah_p + kk * 32);
    #pragma unroll
    for (int nt = 0; nt < 4; nt++) {
      const size_t nrow = (size_t)(n0 + nt * 16 + qc) * 2048 + k0 + kk * 32 + g * 8;
      bf16x8 bh = ld8(Wh + nrow);
      acc[nt] = mfma16(ah, bh, acc[nt]);
    }
  }
  #pragma unroll
  for (int nt = 0; nt < 4; nt++) {
    const int n = n0 + nt * 16 + qc;
    const float bb = (blockIdx.z == 0) ? bo[n] : 0.f;
    #pragma unroll
    for (int r = 0; r < 4; r++)
      unsafeAtomicAdd(&out[(m0 + g * 4 + r) * 256 + n], acc[nt][r] + bb);
  }
}

extern "C" void kernel_launch(void* const* d_in, const int* in_sizes, int n_in,
                              void* d_out, int out_size, void* d_ws, size_t ws_size,
                              hipStream_t stream) {
  const float* x  = (const float*)d_in[0];
  const float* Wq = (const float*)d_in[1];
  const float* bq = (const float*)d_in[2];
  const float* Wk = (const float*)d_in[3];
  const float* bk = (const float*)d_in[4];
  const float* Wv = (const float*)d_in[5];
  const float* bv = (const float*)d_in[6];
  const float* Wo = (const float*)d_in[7];
  const float* bo = (const float*)d_in[8];
  char* p = (char*)d_ws;
  __bf16* xb  = (__bf16*)(p);                          // 2 MB  [4096][256]
  __bf16* Wt  = (__bf16*)(p + (2ull  << 20));          // 3 MB  [3][8][256 e][256 d]
  __bf16* Woh = (__bf16*)(p + (5ull  << 20));          // 1 MB  [256 n][2048 k]
  __bf16* Qb  = (__bf16*)(p + (7ull  << 20));          // 16 MB [bh][s][d] (scale folded)
  __bf16* Kb  = (__bf16*)(p + (23ull << 20));          // 16 MB [bh][s][d]
  __bf16* Vtb = (__bf16*)(p + (39ull << 20));          // 16 MB [bh][d][s]
  __bf16* Ohb = (__bf16*)(p + (55ull << 20));          // 16 MB [bs][h*d]

  k_prep<<<dim3(3072), dim3(256), 0, stream>>>(x, Wq, Wk, Wv, Wo, xb, Wt, Woh);
  k_qkv<<<dim3(16, 4, 16), dim3(256), 0, stream>>>(xb, Wt, bq, bk, bv, Qb, Kb, Vtb);
  k_attn<<<dim3(256), dim3(256), 0, stream>>>(Qb, Kb, Vtb, Ohb);
  (void)hipMemsetAsync(d_out, 0, (size_t)out_size * sizeof(float), stream);
  k_out<<<dim3(64, 4, 4), dim3(256), 0, stream>>>(Ohb, Woh, bo, (float*)d_out);
}